// Round 5
// baseline (805.527 us; speedup 1.0000x reference)
//
#include <hip/hip_runtime.h>

// Mamba selective scan, fp32. u,delta,z:(4,2048,2048) A:(2048,16)
// B,C:(4,16,2048) D:(2048,). Output y:(4,2048,2048).
// 3-pass chunked scan: chunk operator is (S=sum dt, q=local scan), since
// prod_t exp(dt_t*A[n]) == exp(A[n]*sum_t dt_t).
// R4b: NC=64 (2048 blocks, one 32-step tile per thread) for latency hiding;
// non-temporal loads/stores on u/delta/z/y streams via ext_vector_type
// (HIP_vector_type structs are rejected by the nontemporal builtins);
// pass2 parallelized over the 16 states.

#define BATCHSZ 4
#define DIN 2048
#define NSTATE 16
#define SEQ 2048
#define NCH (BATCHSZ * DIN)     // 8192 channels
#define TT 32                   // time tile: 128 B per stream per thread
#define L2E 1.44269504f

typedef float f4 __attribute__((ext_vector_type(4)));

__device__ __forceinline__ float softplus_f(float v) {
    float e = __builtin_amdgcn_exp2f(v * L2E);
    return 0.69314718f * __builtin_amdgcn_logf(1.0f + e);
}

__device__ __forceinline__ float silu_f(float v) {
    float s = __builtin_amdgcn_rcpf(1.0f + __builtin_amdgcn_exp2f(-v * L2E));
    return v * s;
}

// ws layout (SoA, fully coalesced in every pass):
//   wsq[(n*NC + c)*NCH + bd]   n in [0,16)
//   wsS[c*NCH + bd]            at offset 16*NC*NCH

// Pass 1: per (b,d,chunk) local scan from zero state -> (q[16], S)
template<int NC>
__global__ __launch_bounds__(256, 4) void k_pass1(
        const float* __restrict__ u, const float* __restrict__ delta,
        const float* __restrict__ A, const float* __restrict__ Bm,
        float* __restrict__ ws) {
    constexpr int LC = SEQ / NC;
    constexpr int DB = DIN / 256;
    int blk = blockIdx.x;
    int b = (blk / DB) % BATCHSZ;           // wave-uniform (from blockIdx)
    int c = blk / (DB * BATCHSZ);           // wave-uniform
    int d = (blk % DB) * 256 + threadIdx.x;
    int bd = b * DIN + d;

    float A2[NSTATE];
    const float* Ar = A + d * NSTATE;
    #pragma unroll
    for (int n = 0; n < NSTATE; ++n) A2[n] = Ar[n] * L2E;

    float x[NSTATE];
    #pragma unroll
    for (int n = 0; n < NSTATE; ++n) x[n] = 0.0f;
    float S = 0.0f;

    size_t base = (size_t)bd * SEQ + (size_t)c * LC;
    const f4* u4 = (const f4*)(u + base);
    const f4* d4 = (const f4*)(delta + base);
    const float* Bp = Bm + (size_t)b * NSTATE * SEQ + (size_t)c * LC;  // uniform

    for (int tile = 0; tile < LC / TT; ++tile) {
        f4 ub[8], db[8];
        #pragma unroll
        for (int j = 0; j < 8; ++j) {
            ub[j] = __builtin_nontemporal_load(&u4[tile * 8 + j]);
            db[j] = __builtin_nontemporal_load(&d4[tile * 8 + j]);
        }
        #pragma unroll
        for (int j = 0; j < 8; ++j) {
            #pragma unroll
            for (int k = 0; k < 4; ++k) {
                float dt = softplus_f(db[j][k]);
                S += dt;
                float du = dt * ub[j][k];
                int t = tile * TT + j * 4 + k;
                #pragma unroll
                for (int n = 0; n < NSTATE; ++n) {
                    float dA = __builtin_amdgcn_exp2f(A2[n] * dt);
                    x[n] = x[n] * dA + du * Bp[n * SEQ + t];
                }
            }
        }
    }
    float* wsq = ws;
    float* wsS = ws + (size_t)NSTATE * NC * NCH;
    #pragma unroll
    for (int n = 0; n < NSTATE; ++n) wsq[((size_t)n * NC + c) * NCH + bd] = x[n];
    wsS[(size_t)c * NCH + bd] = S;
}

// Pass 2: combine chunk operators sequentially per (bd, n); overwrite q with
// the chunk's INITIAL state (prefix), in place. One thread per (bd, n).
template<int NC>
__global__ __launch_bounds__(256) void k_pass2(
        const float* __restrict__ A, float* __restrict__ ws) {
    int blk = blockIdx.x;                   // NSTATE * (NCH/256) blocks
    int n  = blk >> 5;                      // NCH/256 = 32
    int bd = (blk & 31) * 256 + threadIdx.x;
    int d  = bd & (DIN - 1);

    float A2 = A[d * NSTATE + n] * L2E;

    float* wsq = ws;
    float* wsS = ws + (size_t)NSTATE * NC * NCH;

    float x = 0.0f;
    for (int c = 0; c < NC; ++c) {
        float S = wsS[(size_t)c * NCH + bd];
        float* p = wsq + ((size_t)n * NC + c) * NCH + bd;
        float q = *p;
        float P = __builtin_amdgcn_exp2f(A2 * S);
        *p = x;                              // initial state for chunk c
        x = x * P + q;
    }
}

// Pass 3: per (b,d,chunk) rescan from the chunk's initial state; emit y.
template<int NC>
__global__ __launch_bounds__(256, 4) void k_pass3(
        const float* __restrict__ u, const float* __restrict__ delta,
        const float* __restrict__ A, const float* __restrict__ Bm,
        const float* __restrict__ Cm, const float* __restrict__ Dv,
        const float* __restrict__ z, const float* __restrict__ ws,
        float* __restrict__ out) {
    constexpr int LC = SEQ / NC;
    constexpr int DB = DIN / 256;
    int blk = blockIdx.x;
    int b = (blk / DB) % BATCHSZ;           // wave-uniform
    int c = blk / (DB * BATCHSZ);           // wave-uniform
    int d = (blk % DB) * 256 + threadIdx.x;
    int bd = b * DIN + d;

    float A2[NSTATE];
    const float* Ar = A + d * NSTATE;
    #pragma unroll
    for (int n = 0; n < NSTATE; ++n) A2[n] = Ar[n] * L2E;

    const float* wsq = ws;
    float x[NSTATE];
    #pragma unroll
    for (int n = 0; n < NSTATE; ++n)
        x[n] = wsq[((size_t)n * NC + c) * NCH + bd];

    float Dd = Dv[d];
    size_t base = (size_t)bd * SEQ + (size_t)c * LC;
    const f4* u4 = (const f4*)(u + base);
    const f4* d4 = (const f4*)(delta + base);
    const f4* z4 = (const f4*)(z + base);
    f4* o4 = (f4*)(out + base);
    const float* Bp = Bm + (size_t)b * NSTATE * SEQ + (size_t)c * LC;  // uniform
    const float* Cp = Cm + (size_t)b * NSTATE * SEQ + (size_t)c * LC;  // uniform

    for (int tile = 0; tile < LC / TT; ++tile) {
        f4 ub[8], db[8];
        #pragma unroll
        for (int j = 0; j < 8; ++j) {
            ub[j] = __builtin_nontemporal_load(&u4[tile * 8 + j]);
            db[j] = __builtin_nontemporal_load(&d4[tile * 8 + j]);
        }
        f4 yy[8];   // pre-gate y; ub/db die as yy is born (flat liveness)
        #pragma unroll
        for (int j = 0; j < 8; ++j) {
            #pragma unroll
            for (int k = 0; k < 4; ++k) {
                float uv = ub[j][k];
                float dt = softplus_f(db[j][k]);
                float du = dt * uv;
                int t = tile * TT + j * 4 + k;
                float acc = 0.0f;
                #pragma unroll
                for (int n = 0; n < NSTATE; ++n) {
                    float dA = __builtin_amdgcn_exp2f(A2[n] * dt);
                    x[n] = x[n] * dA + du * Bp[n * SEQ + t];
                    acc += x[n] * Cp[n * SEQ + t];
                }
                yy[j][k] = acc + Dd * uv;
            }
        }
        f4 zb[8];
        #pragma unroll
        for (int j = 0; j < 8; ++j) zb[j] = __builtin_nontemporal_load(&z4[tile * 8 + j]);
        #pragma unroll
        for (int j = 0; j < 8; ++j) {
            f4 oo;
            #pragma unroll
            for (int k = 0; k < 4; ++k)
                oo[k] = yy[j][k] * silu_f(zb[j][k]);
            __builtin_nontemporal_store(oo, &o4[tile * 8 + j]);
        }
    }
}

// Fallback if ws is too small: one thread per (b,d), full sequential scan.
__global__ __launch_bounds__(256) void k_simple(
        const float* __restrict__ u, const float* __restrict__ delta,
        const float* __restrict__ A, const float* __restrict__ Bm,
        const float* __restrict__ Cm, const float* __restrict__ Dv,
        const float* __restrict__ z, float* __restrict__ out) {
    int bd = blockIdx.x * 256 + threadIdx.x;
    int b  = bd >> 11;
    int d  = bd & (DIN - 1);

    float A2[NSTATE];
    const float* Ar = A + d * NSTATE;
    #pragma unroll
    for (int n = 0; n < NSTATE; ++n) A2[n] = Ar[n] * L2E;
    float x[NSTATE];
    #pragma unroll
    for (int n = 0; n < NSTATE; ++n) x[n] = 0.0f;

    float Dd = Dv[d];
    size_t base = (size_t)bd * SEQ;
    const f4* u4 = (const f4*)(u + base);
    const f4* d4 = (const f4*)(delta + base);
    const f4* z4 = (const f4*)(z + base);
    f4* o4 = (f4*)(out + base);
    const float* Bp = Bm + (size_t)b * NSTATE * SEQ;
    const float* Cp = Cm + (size_t)b * NSTATE * SEQ;

    for (int t4 = 0; t4 < SEQ / 4; ++t4) {
        f4 uu = u4[t4];
        f4 dd = d4[t4];
        f4 zz = z4[t4];
        f4 yy;
        #pragma unroll
        for (int k = 0; k < 4; ++k) {
            float uv = uu[k];
            float dt = softplus_f(dd[k]);
            float du = dt * uv;
            int t = t4 * 4 + k;
            float acc = 0.0f;
            #pragma unroll
            for (int n = 0; n < NSTATE; ++n) {
                float dA = __builtin_amdgcn_exp2f(A2[n] * dt);
                x[n] = x[n] * dA + du * Bp[n * SEQ + t];
                acc += x[n] * Cp[n * SEQ + t];
            }
            float y = acc + Dd * uv;
            yy[k] = y * silu_f(zz[k]);
        }
        o4[t4] = yy;
    }
}

template<int NC>
static void launch_chunked(const float* u, const float* delta, const float* A,
                           const float* Bm, const float* Cm, const float* Dv,
                           const float* z, float* ws, float* out, hipStream_t stream) {
    k_pass1<NC><<<NCH * NC / 256, 256, 0, stream>>>(u, delta, A, Bm, ws);
    k_pass2<NC><<<NSTATE * (NCH / 256), 256, 0, stream>>>(A, ws);
    k_pass3<NC><<<NCH * NC / 256, 256, 0, stream>>>(u, delta, A, Bm, Cm, Dv, z, ws, out);
}

extern "C" void kernel_launch(void* const* d_in, const int* in_sizes, int n_in,
                              void* d_out, int out_size, void* d_ws, size_t ws_size,
                              hipStream_t stream) {
    const float* u     = (const float*)d_in[0];
    const float* delta = (const float*)d_in[1];
    const float* A     = (const float*)d_in[2];
    const float* Bm    = (const float*)d_in[3];
    const float* Cm    = (const float*)d_in[4];
    const float* Dv    = (const float*)d_in[5];
    const float* z     = (const float*)d_in[6];
    float* out = (float*)d_out;
    float* ws = (float*)d_ws;

    size_t need64 = (size_t)(NSTATE + 1) * 64 * NCH * sizeof(float);
    size_t need32 = (size_t)(NSTATE + 1) * 32 * NCH * sizeof(float);
    size_t need16 = (size_t)(NSTATE + 1) * 16 * NCH * sizeof(float);
    if (ws_size >= need64) {
        launch_chunked<64>(u, delta, A, Bm, Cm, Dv, z, ws, out, stream);
    } else if (ws_size >= need32) {
        launch_chunked<32>(u, delta, A, Bm, Cm, Dv, z, ws, out, stream);
    } else if (ws_size >= need16) {
        launch_chunked<16>(u, delta, A, Bm, Cm, Dv, z, ws, out, stream);
    } else {
        k_simple<<<NCH / 256, 256, 0, stream>>>(u, delta, A, Bm, Cm, Dv, z, out);
    }
}